// Round 1
// baseline (1106.526 us; speedup 1.0000x reference)
//
#include <hip/hip_runtime.h>
#include <math.h>

// Problem constants (derived from in_sizes at launch for safety)
#define FDIM 64
#define HDIM 128
#define CLSD 64

__device__ __forceinline__ float sigmoidf_(float x){ return 1.0f/(1.0f+expf(-x)); }

// agg = 0, deg = 1 (self-loop pre-counted)
__global__ void k_init(float* __restrict__ agg, float* __restrict__ deg, int N){
    int i = blockIdx.x*blockDim.x + threadIdx.x;
    int stride = gridDim.x*blockDim.x;
    int total = N*FDIM;
    for (int idx = i; idx < total; idx += stride) agg[idx] = 0.0f;
    for (int idx = i; idx < N;     idx += stride) deg[idx] = 1.0f;
}

// xw = x @ W_gcn   ([N,64] @ [64,64]); 4 nodes per 256-thread block, W in LDS
__global__ void k_xw(const float* __restrict__ x, const float* __restrict__ W,
                     float* __restrict__ xw, int N){
    __shared__ float Wl[64*64];
    __shared__ float xs[4*64];
    int t = threadIdx.x;
    const float4* W4 = (const float4*)W;
    float4* Wl4 = (float4*)Wl;
    #pragma unroll
    for (int i = 0; i < 4; ++i) Wl4[i*256 + t] = W4[i*256 + t];   // 4096 floats
    int nb = blockIdx.x*4;
    if (nb >= N) return;
    xs[t] = x[(size_t)nb*64 + t];
    __syncthreads();
    int m = t >> 6, c = t & 63;
    const float* xr = &xs[m*64];
    float acc = 0.0f;
    #pragma unroll
    for (int k = 0; k < 64; ++k) acc += xr[k]*Wl[k*64 + c];
    xw[(size_t)(nb+m)*64 + c] = acc;
}

__global__ void k_deg(const int* __restrict__ ei, float* __restrict__ deg, int E){
    int i = blockIdx.x*blockDim.x + threadIdx.x;
    if (i < E) atomicAdd(&deg[ei[E + i]], 1.0f);
}

__global__ void k_dinv(float* __restrict__ deg, int N){
    int i = blockIdx.x*blockDim.x + threadIdx.x;
    if (i < N) deg[i] = rsqrtf(deg[i]);   // deg >= 1 always (self loop)
}

// agg[dst] += dinv[src]*dinv[dst] * xw[src];  16 lanes (x float4) per edge
__global__ void k_agg(const int* __restrict__ ei, const float* __restrict__ dinv,
                      const float* __restrict__ xw, float* __restrict__ agg, int E){
    int tid = blockIdx.x*256 + threadIdx.x;
    int e = tid >> 4, l = tid & 15;
    if (e >= E) return;
    int s = ei[e], d = ei[E + e];
    float nrm = dinv[s]*dinv[d];
    float4 v = ((const float4*)xw)[(size_t)s*16 + l];
    float* ap = &agg[(size_t)d*64 + l*4];
    atomicAdd(ap+0, nrm*v.x);
    atomicAdd(ap+1, nrm*v.y);
    atomicAdd(ap+2, nrm*v.z);
    atomicAdd(ap+3, nrm*v.w);
}

// self-loop + bias:  agg[i][f] += dinv[i]^2 * xw[i][f] + b_gcn[f]   (now agg == h)
__global__ void k_self(const float* __restrict__ dinv, const float* __restrict__ xw,
                       const float* __restrict__ bg, float* __restrict__ agg, int N){
    int i = blockIdx.x*blockDim.x + threadIdx.x;
    if (i < N*FDIM){
        int n = i >> 6, f = i & 63;
        float di = dinv[n];
        agg[i] += di*di*xw[i] + bg[f];
    }
}

// Fused: gates GEMM ([h|h1] @ [Wx;Th] + biases) -> LSTM cell -> relu -> logits
//        -> softmax -> z.  16 nodes per 256-thread block.
__launch_bounds__(256)
__global__ void k_fused(const float* __restrict__ h,  const float* __restrict__ h1,
                        const float* __restrict__ h2,
                        const float* __restrict__ Wx, const float* __restrict__ Th,
                        const float* __restrict__ bgate, const float* __restrict__ bconv,
                        const float* __restrict__ wc, const float* __restrict__ Wlin,
                        const float* __restrict__ blin,
                        float* __restrict__ outC, float* __restrict__ z, int N)
{
    __shared__ float A[16*16];     // A chunk (16 nodes x 16 k)
    __shared__ float Bg[16*512];   // B chunk during GEMM; G tile afterwards (32 KiB)
    __shared__ float Hn[16*128];   // relu(Hn) tile (8 KiB)

    int t  = threadIdx.x;
    int nb = blockIdx.x * 16;
    int ng = t >> 6;               // node group 0..3 (4 nodes each)
    int cg = t & 63;               // col group (8 cols each)

    float acc[4][8];
    #pragma unroll
    for (int j = 0; j < 8; ++j){
        int c = cg*8 + j;
        float b = bgate[c] + bconv[c];
        #pragma unroll
        for (int mm = 0; mm < 4; ++mm) acc[mm][j] = b;
    }

    for (int kk = 0; kk < 12; ++kk){
        // stage A: thread -> (m, k_local)
        {
            int m = t >> 4, kl = t & 15;
            int kg = kk*16 + kl;
            float v = (kg < 64) ? h[(size_t)(nb+m)*64 + kg]
                                : h1[(size_t)(nb+m)*128 + (kg - 64)];
            A[m*16 + kl] = v;
        }
        // stage B: 16 rows x 512 cols, float4 loads
        #pragma unroll
        for (int i = 0; i < 8; ++i){
            int lin4 = i*256 + t;                 // 0..2047
            int row = lin4 >> 7, col4 = lin4 & 127;
            int kg = kk*16 + row;
            float4 v = (kg < 64) ? ((const float4*)Wx)[(size_t)kg*128 + col4]
                                 : ((const float4*)Th)[(size_t)(kg-64)*128 + col4];
            ((float4*)Bg)[row*128 + col4] = v;
        }
        __syncthreads();
        #pragma unroll
        for (int k = 0; k < 16; ++k){
            float a0 = A[(ng*4+0)*16 + k];
            float a1 = A[(ng*4+1)*16 + k];
            float a2 = A[(ng*4+2)*16 + k];
            float a3 = A[(ng*4+3)*16 + k];
            float4 b0 = ((const float4*)Bg)[k*128 + cg*2 + 0];
            float4 b1 = ((const float4*)Bg)[k*128 + cg*2 + 1];
            float bv[8] = {b0.x,b0.y,b0.z,b0.w,b1.x,b1.y,b1.z,b1.w};
            #pragma unroll
            for (int j = 0; j < 8; ++j){
                acc[0][j] += a0*bv[j];
                acc[1][j] += a1*bv[j];
                acc[2][j] += a2*bv[j];
                acc[3][j] += a3*bv[j];
            }
        }
        __syncthreads();
    }

    // dump G (gate pre-activations) into Bg
    #pragma unroll
    for (int mm = 0; mm < 4; ++mm){
        int m = ng*4 + mm;
        ((float4*)&Bg[m*512])[cg*2 + 0] = make_float4(acc[mm][0],acc[mm][1],acc[mm][2],acc[mm][3]);
        ((float4*)&Bg[m*512])[cg*2 + 1] = make_float4(acc[mm][4],acc[mm][5],acc[mm][6],acc[mm][7]);
    }
    __syncthreads();

    // LSTM elementwise over 16x128
    #pragma unroll
    for (int i = 0; i < 8; ++i){
        int lin = i*256 + t;
        int m = lin >> 7, c = lin & 127;
        const float* g = &Bg[m*512];
        float gi = g[c], gf = g[128+c], gc = g[256+c], go = g[384+c];
        float hv = h2[(size_t)(nb+m)*128 + c];
        float I  = sigmoidf_(gi + wc[c]*hv);
        float Fg = sigmoidf_(gf + wc[128+c]*hv);
        float C  = Fg*hv + I*tanhf(gc);
        float O  = sigmoidf_(go + wc[256+c]*C);
        float hn = O*tanhf(C);
        outC[(size_t)(nb+m)*128 + c] = C;
        Hn[m*128 + c] = fmaxf(hn, 0.0f);           // relu fused here
    }
    __syncthreads();

    // logits (relu(Hn) @ W_lin + b_lin) + softmax; 16 lanes per node, 4 cls each
    {
        int m = t >> 4, q = t & 15;
        float4 bl = ((const float4*)blin)[q];
        float l0 = bl.x, l1 = bl.y, l2 = bl.z, l3 = bl.w;
        #pragma unroll
        for (int k = 0; k < 128; ++k){
            float hv = Hn[m*128 + k];
            float4 w = ((const float4*)Wlin)[k*16 + q];
            l0 += hv*w.x; l1 += hv*w.y; l2 += hv*w.z; l3 += hv*w.w;
        }
        float mx = fmaxf(fmaxf(l0,l1), fmaxf(l2,l3));
        #pragma unroll
        for (int off = 1; off < 16; off <<= 1) mx = fmaxf(mx, __shfl_xor(mx, off, 64));
        float e0 = expf(l0-mx), e1 = expf(l1-mx), e2 = expf(l2-mx), e3 = expf(l3-mx);
        float s = e0+e1+e2+e3;
        #pragma unroll
        for (int off = 1; off < 16; off <<= 1) s += __shfl_xor(s, off, 64);
        float inv = 1.0f/s;
        ((float4*)z)[(size_t)(nb+m)*16 + q] = make_float4(e0*inv, e1*inv, e2*inv, e3*inv);
    }
}

// r[e] = dot64(z[src], z[dst]); one wave per edge
__global__ void k_dec(const int* __restrict__ eli, const float* __restrict__ z,
                      float* __restrict__ r, int EL){
    int t = threadIdx.x;
    int e = blockIdx.x*4 + (t >> 6);
    int lane = t & 63;
    if (e >= EL) return;
    int s = eli[e], d = eli[EL + e];
    float p = z[(size_t)s*64 + lane] * z[(size_t)d*64 + lane];
    #pragma unroll
    for (int off = 32; off >= 1; off >>= 1) p += __shfl_xor(p, off, 64);
    if (lane == 0) r[e] = p;
}

extern "C" void kernel_launch(void* const* d_in, const int* in_sizes, int n_in,
                              void* d_out, int out_size, void* d_ws, size_t ws_size,
                              hipStream_t stream)
{
    const float* x   = (const float*)d_in[0];
    const int*   ei  = (const int*)  d_in[1];
    const int*   eli = (const int*)  d_in[2];
    const float* h1  = (const float*)d_in[3];
    const float* h2  = (const float*)d_in[4];
    const float* Wg  = (const float*)d_in[5];
    const float* bg  = (const float*)d_in[6];
    const float* Wx  = (const float*)d_in[7];
    const float* Th  = (const float*)d_in[8];
    const float* bga = (const float*)d_in[9];
    const float* bco = (const float*)d_in[10];
    const float* wc  = (const float*)d_in[11];
    const float* Wl  = (const float*)d_in[12];
    const float* bl  = (const float*)d_in[13];

    const int N  = in_sizes[0] / FDIM;
    const int E  = in_sizes[1] / 2;
    const int EL = in_sizes[2] / 2;

    // workspace layout (floats): xw[N*64] | agg[N*64] | dinv[N] | z[N*64]
    float* ws   = (float*)d_ws;
    float* xw   = ws;
    float* agg  = ws + (size_t)N*64;
    float* dinv = ws + (size_t)N*128;
    float* zbuf = ws + (size_t)N*128 + N;     // N=50000 -> offset divisible by 16

    float* out = (float*)d_out;
    float* r   = out;                          // [EL]
    float* oh1 = out + EL;                     // [N*128] passthrough
    float* oC  = out + EL + (size_t)N*HDIM;    // [N*128]

    k_init <<<2048, 256, 0, stream>>>(agg, dinv, N);
    k_xw   <<<(N + 3)/4, 256, 0, stream>>>(x, Wg, xw, N);
    k_deg  <<<(E + 255)/256, 256, 0, stream>>>(ei, dinv, E);
    k_dinv <<<(N + 255)/256, 256, 0, stream>>>(dinv, N);
    k_agg  <<<(E*16 + 255)/256, 256, 0, stream>>>(ei, dinv, xw, agg, E);
    k_self <<<(N*FDIM + 255)/256, 256, 0, stream>>>(dinv, xw, bg, agg, N);
    k_fused<<<(N + 15)/16, 256, 0, stream>>>(agg, h1, h2, Wx, Th, bga, bco, wc, Wl, bl,
                                             oC, zbuf, N);
    hipMemcpyAsync(oh1, h1, (size_t)N*HDIM*sizeof(float), hipMemcpyDeviceToDevice, stream);
    k_dec  <<<(EL + 3)/4, 256, 0, stream>>>(eli, zbuf, r, EL);
}

// Round 2
// 598.234 us; speedup vs baseline: 1.8497x; 1.8497x over previous
//
#include <hip/hip_runtime.h>
#include <math.h>

#define FDIM 64
#define HDIM 128
#define CLSD 64

__device__ __forceinline__ float sigmoidf_(float x){ return 1.0f/(1.0f+expf(-x)); }

// zero the degree-count array
__global__ void k_init(int* __restrict__ cnt, int N){
    int i = blockIdx.x*blockDim.x + threadIdx.x;
    if (i < N) cnt[i] = 0;
}

// xw = x @ W_gcn   ([N,64] @ [64,64]); 4 nodes per 256-thread block, W in LDS
__global__ void k_xw(const float* __restrict__ x, const float* __restrict__ W,
                     float* __restrict__ xw, int N){
    __shared__ float Wl[64*64];
    __shared__ float xs[4*64];
    int t = threadIdx.x;
    const float4* W4 = (const float4*)W;
    float4* Wl4 = (float4*)Wl;
    #pragma unroll
    for (int i = 0; i < 4; ++i) Wl4[i*256 + t] = W4[i*256 + t];
    int nb = blockIdx.x*4;
    if (nb >= N) return;
    xs[t] = x[(size_t)nb*64 + t];
    __syncthreads();
    int m = t >> 6, c = t & 63;
    const float* xr = &xs[m*64];
    float acc = 0.0f;
    #pragma unroll
    for (int k = 0; k < 64; ++k) acc += xr[k]*Wl[k*64 + c];
    xw[(size_t)(nb+m)*64 + c] = acc;
}

// in-degree histogram (real edges only; self-loop folded in later)
__global__ void k_deg(const int* __restrict__ ei, int* __restrict__ cnt, int E){
    int i = blockIdx.x*blockDim.x + threadIdx.x;
    if (i < E) atomicAdd(&cnt[ei[E + i]], 1);
}

// single-block exclusive scan over cnt[N] -> off[N+1]; also primes cur = off
__launch_bounds__(1024)
__global__ void k_scan(const int* __restrict__ cnt, int* __restrict__ off,
                       int* __restrict__ cur, int N){
    __shared__ int sums[1024];
    int t = threadIdx.x;
    int chunk = (N + 1023) >> 10;
    int lo = t*chunk;
    int hi = lo + chunk; if (hi > N) hi = N;
    int s = 0;
    for (int i = lo; i < hi; ++i) s += cnt[i];
    sums[t] = s;
    __syncthreads();
    for (int d = 1; d < 1024; d <<= 1){
        int v = (t >= d) ? sums[t-d] : 0;
        __syncthreads();
        if (t >= d) sums[t] += v;
        __syncthreads();
    }
    int run = (t > 0) ? sums[t-1] : 0;
    for (int i = lo; i < hi; ++i){
        off[i] = run; cur[i] = run;
        run += cnt[i];
    }
    if (t == 1023) off[N] = sums[1023];
}

// dinv[n] = rsqrt(deg_in + 1)  (+1 = self loop)
__global__ void k_dinv(const int* __restrict__ cnt, float* __restrict__ dinv, int N){
    int i = blockIdx.x*blockDim.x + threadIdx.x;
    if (i < N) dinv[i] = rsqrtf((float)cnt[i] + 1.0f);
}

// bucket-fill CSR: csr[slot(dst)] = src
__global__ void k_fill(const int* __restrict__ ei, int* __restrict__ cur,
                       int* __restrict__ csr, int E){
    int i = blockIdx.x*blockDim.x + threadIdx.x;
    if (i < E){
        int s = ei[i], d = ei[E + i];
        int slot = atomicAdd(&cur[d], 1);
        csr[slot] = s;
    }
}

// h[n] = dinv[n]*( sum_{s in nbrs(n)} dinv[s]*xw[s] + dinv[n]*xw[n] ) + b_gcn
// 16 lanes per node, float4 per lane. No atomics; xw is L2/L3-resident.
__global__ void k_gather(const int* __restrict__ off, const int* __restrict__ csr,
                         const float* __restrict__ dinv, const float* __restrict__ xw,
                         const float* __restrict__ bg, float* __restrict__ h, int N){
    int tid = blockIdx.x*256 + threadIdx.x;
    int n = tid >> 4, l = tid & 15;
    if (n >= N) return;
    int beg = off[n], end = off[n+1];
    const float4* xw4 = (const float4*)xw;
    float4 acc = make_float4(0.f,0.f,0.f,0.f);
    for (int idx = beg; idx < end; ++idx){
        int s = csr[idx];
        float w = dinv[s];
        float4 v = xw4[(size_t)s*16 + l];
        acc.x += w*v.x; acc.y += w*v.y; acc.z += w*v.z; acc.w += w*v.w;
    }
    float dn = dinv[n];
    float4 sv = xw4[(size_t)n*16 + l];
    float4 b4 = ((const float4*)bg)[l];
    acc.x = dn*(acc.x + dn*sv.x) + b4.x;
    acc.y = dn*(acc.y + dn*sv.y) + b4.y;
    acc.z = dn*(acc.z + dn*sv.z) + b4.z;
    acc.w = dn*(acc.w + dn*sv.w) + b4.w;
    ((float4*)h)[(size_t)n*16 + l] = acc;
}

// Fused: gates GEMM ([h|h1] @ [Wx;Th] + biases) -> LSTM cell -> relu -> logits
//        -> softmax -> z.  16 nodes per 256-thread block.
__launch_bounds__(256)
__global__ void k_fused(const float* __restrict__ h,  const float* __restrict__ h1,
                        const float* __restrict__ h2,
                        const float* __restrict__ Wx, const float* __restrict__ Th,
                        const float* __restrict__ bgate, const float* __restrict__ bconv,
                        const float* __restrict__ wc, const float* __restrict__ Wlin,
                        const float* __restrict__ blin,
                        float* __restrict__ outC, float* __restrict__ z, int N)
{
    __shared__ float A[16*16];
    __shared__ float Bg[16*512];
    __shared__ float Hn[16*128];

    int t  = threadIdx.x;
    int nb = blockIdx.x * 16;
    int ng = t >> 6;
    int cg = t & 63;

    float acc[4][8];
    #pragma unroll
    for (int j = 0; j < 8; ++j){
        int c = cg*8 + j;
        float b = bgate[c] + bconv[c];
        #pragma unroll
        for (int mm = 0; mm < 4; ++mm) acc[mm][j] = b;
    }

    for (int kk = 0; kk < 12; ++kk){
        {
            int m = t >> 4, kl = t & 15;
            int kg = kk*16 + kl;
            float v = (kg < 64) ? h[(size_t)(nb+m)*64 + kg]
                                : h1[(size_t)(nb+m)*128 + (kg - 64)];
            A[m*16 + kl] = v;
        }
        #pragma unroll
        for (int i = 0; i < 8; ++i){
            int lin4 = i*256 + t;
            int row = lin4 >> 7, col4 = lin4 & 127;
            int kg = kk*16 + row;
            float4 v = (kg < 64) ? ((const float4*)Wx)[(size_t)kg*128 + col4]
                                 : ((const float4*)Th)[(size_t)(kg-64)*128 + col4];
            ((float4*)Bg)[row*128 + col4] = v;
        }
        __syncthreads();
        #pragma unroll
        for (int k = 0; k < 16; ++k){
            float a0 = A[(ng*4+0)*16 + k];
            float a1 = A[(ng*4+1)*16 + k];
            float a2 = A[(ng*4+2)*16 + k];
            float a3 = A[(ng*4+3)*16 + k];
            float4 b0 = ((const float4*)Bg)[k*128 + cg*2 + 0];
            float4 b1 = ((const float4*)Bg)[k*128 + cg*2 + 1];
            float bv[8] = {b0.x,b0.y,b0.z,b0.w,b1.x,b1.y,b1.z,b1.w};
            #pragma unroll
            for (int j = 0; j < 8; ++j){
                acc[0][j] += a0*bv[j];
                acc[1][j] += a1*bv[j];
                acc[2][j] += a2*bv[j];
                acc[3][j] += a3*bv[j];
            }
        }
        __syncthreads();
    }

    #pragma unroll
    for (int mm = 0; mm < 4; ++mm){
        int m = ng*4 + mm;
        ((float4*)&Bg[m*512])[cg*2 + 0] = make_float4(acc[mm][0],acc[mm][1],acc[mm][2],acc[mm][3]);
        ((float4*)&Bg[m*512])[cg*2 + 1] = make_float4(acc[mm][4],acc[mm][5],acc[mm][6],acc[mm][7]);
    }
    __syncthreads();

    #pragma unroll
    for (int i = 0; i < 8; ++i){
        int lin = i*256 + t;
        int m = lin >> 7, c = lin & 127;
        const float* g = &Bg[m*512];
        float gi = g[c], gf = g[128+c], gc = g[256+c], go = g[384+c];
        float hv = h2[(size_t)(nb+m)*128 + c];
        float I  = sigmoidf_(gi + wc[c]*hv);
        float Fg = sigmoidf_(gf + wc[128+c]*hv);
        float C  = Fg*hv + I*tanhf(gc);
        float O  = sigmoidf_(go + wc[256+c]*C);
        float hn = O*tanhf(C);
        outC[(size_t)(nb+m)*128 + c] = C;
        Hn[m*128 + c] = fmaxf(hn, 0.0f);
    }
    __syncthreads();

    {
        int m = t >> 4, q = t & 15;
        float4 bl = ((const float4*)blin)[q];
        float l0 = bl.x, l1 = bl.y, l2 = bl.z, l3 = bl.w;
        #pragma unroll
        for (int k = 0; k < 128; ++k){
            float hv = Hn[m*128 + k];
            float4 w = ((const float4*)Wlin)[k*16 + q];
            l0 += hv*w.x; l1 += hv*w.y; l2 += hv*w.z; l3 += hv*w.w;
        }
        float mx = fmaxf(fmaxf(l0,l1), fmaxf(l2,l3));
        #pragma unroll
        for (int off = 1; off < 16; off <<= 1) mx = fmaxf(mx, __shfl_xor(mx, off, 64));
        float e0 = expf(l0-mx), e1 = expf(l1-mx), e2 = expf(l2-mx), e3 = expf(l3-mx);
        float s = e0+e1+e2+e3;
        #pragma unroll
        for (int off = 1; off < 16; off <<= 1) s += __shfl_xor(s, off, 64);
        float inv = 1.0f/s;
        ((float4*)z)[(size_t)(nb+m)*16 + q] = make_float4(e0*inv, e1*inv, e2*inv, e3*inv);
    }
}

// r[e] = dot64(z[src], z[dst]); 4 edges per 256-thread block
__global__ void k_dec(const int* __restrict__ eli, const float* __restrict__ z,
                      float* __restrict__ r, int EL){
    int t = threadIdx.x;
    int e = blockIdx.x*4 + (t >> 6);
    int lane = t & 63;
    if (e >= EL) return;
    int s = eli[e], d = eli[EL + e];
    float p = z[(size_t)s*64 + lane] * z[(size_t)d*64 + lane];
    #pragma unroll
    for (int off = 32; off >= 1; off >>= 1) p += __shfl_xor(p, off, 64);
    if (lane == 0) r[e] = p;
}

extern "C" void kernel_launch(void* const* d_in, const int* in_sizes, int n_in,
                              void* d_out, int out_size, void* d_ws, size_t ws_size,
                              hipStream_t stream)
{
    const float* x   = (const float*)d_in[0];
    const int*   ei  = (const int*)  d_in[1];
    const int*   eli = (const int*)  d_in[2];
    const float* h1  = (const float*)d_in[3];
    const float* h2  = (const float*)d_in[4];
    const float* Wg  = (const float*)d_in[5];
    const float* bg  = (const float*)d_in[6];
    const float* Wx  = (const float*)d_in[7];
    const float* Th  = (const float*)d_in[8];
    const float* bga = (const float*)d_in[9];
    const float* bco = (const float*)d_in[10];
    const float* wc  = (const float*)d_in[11];
    const float* Wl  = (const float*)d_in[12];
    const float* bl  = (const float*)d_in[13];

    const int N  = in_sizes[0] / FDIM;
    const int E  = in_sizes[1] / 2;
    const int EL = in_sizes[2] / 2;

    // workspace layout (4-byte units):
    // xw[N*64] | h[N*64] | z[N*64] | dinv[N] | cnt[N] | off[N+1] | cur[N] | csr[E]
    float* ws   = (float*)d_ws;
    float* xw   = ws;
    float* hbuf = xw + (size_t)N*64;
    float* zbuf = hbuf + (size_t)N*64;
    float* dinv = zbuf + (size_t)N*64;
    int*   cnt  = (int*)(dinv + N);
    int*   off  = cnt + N;
    int*   cur  = off + N + 1;
    int*   csr  = cur + N;

    float* out = (float*)d_out;
    float* r   = out;                          // [EL]
    float* oh1 = out + EL;                     // [N*128] passthrough
    float* oC  = out + EL + (size_t)N*HDIM;    // [N*128]

    k_init  <<<(N + 255)/256, 256, 0, stream>>>(cnt, N);
    k_xw    <<<(N + 3)/4, 256, 0, stream>>>(x, Wg, xw, N);
    k_deg   <<<(E + 255)/256, 256, 0, stream>>>(ei, cnt, E);
    k_scan  <<<1, 1024, 0, stream>>>(cnt, off, cur, N);
    k_dinv  <<<(N + 255)/256, 256, 0, stream>>>(cnt, dinv, N);
    k_fill  <<<(E + 255)/256, 256, 0, stream>>>(ei, cur, csr, E);
    k_gather<<<(N*16 + 255)/256, 256, 0, stream>>>(off, csr, dinv, xw, bg, hbuf, N);
    k_fused <<<(N + 15)/16, 256, 0, stream>>>(hbuf, h1, h2, Wx, Th, bga, bco, wc, Wl, bl,
                                              oC, zbuf, N);
    hipMemcpyAsync(oh1, h1, (size_t)N*HDIM*sizeof(float), hipMemcpyDeviceToDevice, stream);
    k_dec   <<<(EL + 3)/4, 256, 0, stream>>>(eli, zbuf, r, EL);
}

// Round 3
// 391.147 us; speedup vs baseline: 2.8289x; 1.5294x over previous
//
#include <hip/hip_runtime.h>
#include <math.h>

#define FDIM 64
#define HDIM 128
#define CLSD 64

typedef unsigned short ushort_t;
typedef short bfrag __attribute__((ext_vector_type(8)));   // 8 bf16 (4 VGPRs)
typedef float f32x4 __attribute__((ext_vector_type(4)));

__device__ __forceinline__ float sigmoidf_(float x){ return 1.0f/(1.0f+expf(-x)); }

__device__ __forceinline__ ushort_t f2bf(float f){
    unsigned int u = __float_as_uint(f);
    unsigned int r = (u + 0x7FFFu + ((u >> 16) & 1u)) >> 16;
    return (ushort_t)r;
}
__device__ __forceinline__ float bf2f(ushort_t b){
    return __uint_as_float(((unsigned int)b) << 16);
}

// ---------------- graph prep ----------------

__global__ void k_init(int* __restrict__ cnt, int N){
    int i = blockIdx.x*blockDim.x + threadIdx.x;
    if (i < N) cnt[i] = 0;
}

// xw = x @ W_gcn   ([N,64] @ [64,64]); 4 nodes per 256-thread block, W in LDS
__global__ void k_xw(const float* __restrict__ x, const float* __restrict__ W,
                     float* __restrict__ xw, int N){
    __shared__ float Wl[64*64];
    __shared__ float xs[4*64];
    int t = threadIdx.x;
    const float4* W4 = (const float4*)W;
    float4* Wl4 = (float4*)Wl;
    #pragma unroll
    for (int i = 0; i < 4; ++i) Wl4[i*256 + t] = W4[i*256 + t];
    int nb = blockIdx.x*4;
    if (nb >= N) return;
    xs[t] = x[(size_t)nb*64 + t];
    __syncthreads();
    int m = t >> 6, c = t & 63;
    const float* xr = &xs[m*64];
    float acc = 0.0f;
    #pragma unroll
    for (int k = 0; k < 64; ++k) acc += xr[k]*Wl[k*64 + c];
    xw[(size_t)(nb+m)*64 + c] = acc;
}

__global__ void k_deg(const int* __restrict__ ei, int* __restrict__ cnt, int E){
    int i = blockIdx.x*blockDim.x + threadIdx.x;
    if (i < E) atomicAdd(&cnt[ei[E + i]], 1);
}

__launch_bounds__(1024)
__global__ void k_scan(const int* __restrict__ cnt, int* __restrict__ off,
                       int* __restrict__ cur, int N){
    __shared__ int sums[1024];
    int t = threadIdx.x;
    int chunk = (N + 1023) >> 10;
    int lo = t*chunk;
    int hi = lo + chunk; if (hi > N) hi = N;
    int s = 0;
    for (int i = lo; i < hi; ++i) s += cnt[i];
    sums[t] = s;
    __syncthreads();
    for (int d = 1; d < 1024; d <<= 1){
        int v = (t >= d) ? sums[t-d] : 0;
        __syncthreads();
        if (t >= d) sums[t] += v;
        __syncthreads();
    }
    int run = (t > 0) ? sums[t-1] : 0;
    for (int i = lo; i < hi; ++i){
        off[i] = run; cur[i] = run;
        run += cnt[i];
    }
    if (t == 1023) off[N] = sums[1023];
}

__global__ void k_dinv(const int* __restrict__ cnt, float* __restrict__ dinv, int N){
    int i = blockIdx.x*blockDim.x + threadIdx.x;
    if (i < N) dinv[i] = rsqrtf((float)cnt[i] + 1.0f);
}

__global__ void k_fill(const int* __restrict__ ei, int* __restrict__ cur,
                       int* __restrict__ csr, int E){
    int i = blockIdx.x*blockDim.x + threadIdx.x;
    if (i < E){
        int s = ei[i], d = ei[E + i];
        int slot = atomicAdd(&cur[d], 1);
        csr[slot] = s;
    }
}

__global__ void k_gather(const int* __restrict__ off, const int* __restrict__ csr,
                         const float* __restrict__ dinv, const float* __restrict__ xw,
                         const float* __restrict__ bg, float* __restrict__ h, int N){
    int tid = blockIdx.x*256 + threadIdx.x;
    int n = tid >> 4, l = tid & 15;
    if (n >= N) return;
    int beg = off[n], end = off[n+1];
    const float4* xw4 = (const float4*)xw;
    float4 acc = make_float4(0.f,0.f,0.f,0.f);
    for (int idx = beg; idx < end; ++idx){
        int s = csr[idx];
        float w = dinv[s];
        float4 v = xw4[(size_t)s*16 + l];
        acc.x += w*v.x; acc.y += w*v.y; acc.z += w*v.z; acc.w += w*v.w;
    }
    float dn = dinv[n];
    float4 sv = xw4[(size_t)n*16 + l];
    float4 b4 = ((const float4*)bg)[l];
    acc.x = dn*(acc.x + dn*sv.x) + b4.x;
    acc.y = dn*(acc.y + dn*sv.y) + b4.y;
    acc.z = dn*(acc.z + dn*sv.z) + b4.z;
    acc.w = dn*(acc.w + dn*sv.w) + b4.w;
    ((float4*)h)[(size_t)n*16 + l] = acc;
}

// ---------------- weight prep: bf16 hi/lo splits in MFMA-fragment layout ----------------
// Gate B tile order: T = w*8 + c8, where wave w owns hidden cols hc in [w*32,(w+1)*32),
// c8 = gate*2 + (within>>4).  Fragment: lane = ((k>>3)&3)*16 + (col&15), elem j = k&7.
__global__ void k_prep(const float* __restrict__ Wx, const float* __restrict__ Th,
                       const float* __restrict__ Wl,
                       const float* __restrict__ bga, const float* __restrict__ bco,
                       ushort_t* __restrict__ Bhi, ushort_t* __restrict__ Blo,
                       ushort_t* __restrict__ Lhi, ushort_t* __restrict__ Llo,
                       float* __restrict__ bsum){
    int tid = blockIdx.x*256 + threadIdx.x;
    if (tid < 98304){                       // 192 x 512 gate weights
        int k = tid >> 9, col = tid & 511;
        float v = (k < 64) ? Wx[k*512 + col] : Th[(k-64)*512 + col];
        int g = col >> 7, hc = col & 127;
        int w = hc >> 5, within = hc & 31;
        int c8 = g*2 + (within >> 4);
        int T = w*8 + c8;
        int s = k >> 5;
        int lane = ((k >> 3) & 3)*16 + (within & 15);
        int pos = ((T*6 + s)*64 + lane)*8 + (k & 7);
        ushort_t hb = f2bf(v);
        Bhi[pos] = hb;
        Blo[pos] = f2bf(v - bf2f(hb));
    } else if (tid < 106496){               // 128 x 64 Wlin
        int i = tid - 98304;
        int k = i >> 6, col = i & 63;
        float v = Wl[k*64 + col];
        int ct = col >> 4;
        int s = k >> 5;
        int lane = ((k >> 3) & 3)*16 + (col & 15);
        int pos = ((ct*4 + s)*64 + lane)*8 + (k & 7);
        ushort_t hb = f2bf(v);
        Lhi[pos] = hb;
        Llo[pos] = f2bf(v - bf2f(hb));
    } else if (tid < 107008){
        int c = tid - 106496;
        bsum[c] = bga[c] + bco[c];
    }
}

// ---------------- fused MFMA kernel ----------------
// 32 nodes / block, 4 waves. Gates GEMM (K=192) -> LSTM in-register -> logits GEMM
// (K=128) -> softmax -> z. 3-pass bf16 split for near-fp32 precision.
__launch_bounds__(256)
__global__ void k_fused(const float* __restrict__ h,  const float* __restrict__ h1,
                        const float* __restrict__ h2,
                        const ushort_t* __restrict__ Bhi, const ushort_t* __restrict__ Blo,
                        const ushort_t* __restrict__ Lhi, const ushort_t* __restrict__ Llo,
                        const float* __restrict__ bsum, const float* __restrict__ wc,
                        const float* __restrict__ blin,
                        float* __restrict__ outC, float* __restrict__ z, int N)
{
    __shared__ __align__(16) char smem[25088];
    ushort_t* Ahi = (ushort_t*)smem;            // [768 frags][8] bf16 = 12288 B
    ushort_t* Alo = Ahi + 6144;                 // 12288 B

    const int t    = threadIdx.x;
    const int w    = t >> 6;
    const int lane = t & 63;
    const int nb   = blockIdx.x * 32;

    // ---- stage A = [h | h1] rows nb..nb+31 as bf16 hi/lo fragments ----
    #pragma unroll
    for (int ff = 0; ff < 3; ++ff){
        int f   = ff*256 + t;                   // 0..767
        int mt  = (f >= 384) ? 1 : 0;
        int rem = f - mt*384;
        int s   = rem >> 6, l = rem & 63;
        int row = mt*16 + (l & 15);
        int k0  = s*32 + ((l >> 4) & 3)*8;
        int gr  = nb + row;
        float v[8];
        if (gr < N){
            const float* src = (k0 < 64) ? (h  + (size_t)gr*64  + k0)
                                         : (h1 + (size_t)gr*128 + (k0 - 64));
            float4 p0 = ((const float4*)src)[0];
            float4 p1 = ((const float4*)src)[1];
            v[0]=p0.x; v[1]=p0.y; v[2]=p0.z; v[3]=p0.w;
            v[4]=p1.x; v[5]=p1.y; v[6]=p1.z; v[7]=p1.w;
        } else {
            #pragma unroll
            for (int j = 0; j < 8; ++j) v[j] = 0.0f;
        }
        unsigned int hp[4], lp[4];
        #pragma unroll
        for (int j = 0; j < 4; ++j){
            ushort_t h0 = f2bf(v[2*j]),  h1b = f2bf(v[2*j+1]);
            ushort_t l0 = f2bf(v[2*j]   - bf2f(h0));
            ushort_t l1 = f2bf(v[2*j+1] - bf2f(h1b));
            hp[j] = (unsigned int)h0 | ((unsigned int)h1b << 16);
            lp[j] = (unsigned int)l0 | ((unsigned int)l1  << 16);
        }
        ((int4*)Ahi)[f] = make_int4((int)hp[0],(int)hp[1],(int)hp[2],(int)hp[3]);
        ((int4*)Alo)[f] = make_int4((int)lp[0],(int)lp[1],(int)lp[2],(int)lp[3]);
    }
    __syncthreads();

    // ---- gates GEMM: K=192 (6 steps), 8 col-tiles per wave ----
    f32x4 acc[2][8];
    #pragma unroll
    for (int mt = 0; mt < 2; ++mt)
        #pragma unroll
        for (int c8 = 0; c8 < 8; ++c8)
            acc[mt][c8] = (f32x4){0.f,0.f,0.f,0.f};

    const bfrag* AhiF = (const bfrag*)Ahi;
    const bfrag* AloF = (const bfrag*)Alo;
    const bfrag* BhF  = (const bfrag*)Bhi;
    const bfrag* BlF  = (const bfrag*)Blo;

    #pragma unroll
    for (int s = 0; s < 6; ++s){
        bfrag ah0 = AhiF[(0*6 + s)*64 + lane];
        bfrag ah1 = AhiF[(1*6 + s)*64 + lane];
        bfrag al0 = AloF[(0*6 + s)*64 + lane];
        bfrag al1 = AloF[(1*6 + s)*64 + lane];
        #pragma unroll
        for (int c8 = 0; c8 < 8; ++c8){
            int T = w*8 + c8;
            bfrag bh = BhF[(T*6 + s)*64 + lane];
            bfrag bl = BlF[(T*6 + s)*64 + lane];
            acc[0][c8] = __builtin_amdgcn_mfma_f32_16x16x32_bf16(ah0, bh, acc[0][c8], 0,0,0);
            acc[0][c8] = __builtin_amdgcn_mfma_f32_16x16x32_bf16(ah0, bl, acc[0][c8], 0,0,0);
            acc[0][c8] = __builtin_amdgcn_mfma_f32_16x16x32_bf16(al0, bh, acc[0][c8], 0,0,0);
            acc[1][c8] = __builtin_amdgcn_mfma_f32_16x16x32_bf16(ah1, bh, acc[1][c8], 0,0,0);
            acc[1][c8] = __builtin_amdgcn_mfma_f32_16x16x32_bf16(ah1, bl, acc[1][c8], 0,0,0);
            acc[1][c8] = __builtin_amdgcn_mfma_f32_16x16x32_bf16(al1, bh, acc[1][c8], 0,0,0);
        }
    }
    __syncthreads();    // A region dead; about to reuse smem for Hn/L

    ushort_t* Hhi = (ushort_t*)smem;            // 8192 B (512 frags)
    ushort_t* Hlo = Hhi + 4096;                 // 8192 B
    float*    Ltile = (float*)(smem + 16384);   // [32][68] fp32 = 8704 B

    // ---- LSTM elementwise, fully in-register ----
    // acc[mt][g*2+hc_t][rr] = gate g at (row = mt*16+(lane>>4)*4+rr, hc = w*32+hc_t*16+(lane&15))
    #pragma unroll
    for (int hc_t = 0; hc_t < 2; ++hc_t){
        int hc  = w*32 + hc_t*16 + (lane & 15);
        float bi = bsum[hc],       bfv = bsum[128 + hc];
        float bc = bsum[256 + hc], bo  = bsum[384 + hc];
        float wci = wc[hc], wcf = wc[128 + hc], wco = wc[256 + hc];
        #pragma unroll
        for (int mt = 0; mt < 2; ++mt){
            #pragma unroll
            for (int rr = 0; rr < 4; ++rr){
                int row = mt*16 + ((lane >> 4) & 3)*4 + rr;
                int gr  = nb + row;
                float gi = acc[mt][0 + hc_t][rr] + bi;
                float gf = acc[mt][2 + hc_t][rr] + bfv;
                float gc = acc[mt][4 + hc_t][rr] + bc;
                float go = acc[mt][6 + hc_t][rr] + bo;
                float hv = (gr < N) ? h2[(size_t)gr*128 + hc] : 0.0f;
                float I  = sigmoidf_(gi + wci*hv);
                float Fg = sigmoidf_(gf + wcf*hv);
                float C  = Fg*hv + I*tanhf(gc);
                float O  = sigmoidf_(go + wco*C);
                float hn = O*tanhf(C);
                if (gr < N) outC[(size_t)gr*128 + hc] = C;
                float hr = fmaxf(hn, 0.0f);
                // scatter relu(Hn) as logits-A fragment: k = hc, k-step = w
                int l2  = (row & 15) + (hc_t*2 + ((lane >> 3) & 1))*16;
                int pos = ((mt*4 + w)*64 + l2)*8 + (lane & 7);
                ushort_t hb = f2bf(hr);
                Hhi[pos] = hb;
                Hlo[pos] = f2bf(hr - bf2f(hb));
            }
        }
    }
    __syncthreads();

    // ---- logits GEMM: K=128 (4 steps), wave w owns class-tile w ----
    const bfrag* HhiF = (const bfrag*)Hhi;
    const bfrag* HloF = (const bfrag*)Hlo;
    const bfrag* LhF  = (const bfrag*)Lhi;
    const bfrag* LlF  = (const bfrag*)Llo;
    f32x4 acc2[2];
    acc2[0] = (f32x4){0.f,0.f,0.f,0.f};
    acc2[1] = (f32x4){0.f,0.f,0.f,0.f};
    #pragma unroll
    for (int s = 0; s < 4; ++s){
        bfrag ah0 = HhiF[(0*4 + s)*64 + lane];
        bfrag ah1 = HhiF[(1*4 + s)*64 + lane];
        bfrag al0 = HloF[(0*4 + s)*64 + lane];
        bfrag al1 = HloF[(1*4 + s)*64 + lane];
        bfrag bh  = LhF[(w*4 + s)*64 + lane];
        bfrag bl  = LlF[(w*4 + s)*64 + lane];
        acc2[0] = __builtin_amdgcn_mfma_f32_16x16x32_bf16(ah0, bh, acc2[0], 0,0,0);
        acc2[0] = __builtin_amdgcn_mfma_f32_16x16x32_bf16(ah0, bl, acc2[0], 0,0,0);
        acc2[0] = __builtin_amdgcn_mfma_f32_16x16x32_bf16(al0, bh, acc2[0], 0,0,0);
        acc2[1] = __builtin_amdgcn_mfma_f32_16x16x32_bf16(ah1, bh, acc2[1], 0,0,0);
        acc2[1] = __builtin_amdgcn_mfma_f32_16x16x32_bf16(ah1, bl, acc2[1], 0,0,0);
        acc2[1] = __builtin_amdgcn_mfma_f32_16x16x32_bf16(al1, bh, acc2[1], 0,0,0);
    }
    {
        int cls = w*16 + (lane & 15);
        float bv = blin[cls];
        #pragma unroll
        for (int mt = 0; mt < 2; ++mt){
            #pragma unroll
            for (int rr = 0; rr < 4; ++rr){
                int row = mt*16 + ((lane >> 4) & 3)*4 + rr;
                Ltile[row*68 + cls] = acc2[mt][rr] + bv;
            }
        }
    }
    __syncthreads();

    // ---- softmax + z write: 8 threads per node ----
    {
        int m = t >> 3, q = t & 7;
        const float4* Lr = (const float4*)&Ltile[m*68 + q*8];
        float4 v0 = Lr[0], v1 = Lr[1];
        float mx = fmaxf(fmaxf(fmaxf(v0.x,v0.y),fmaxf(v0.z,v0.w)),
                         fmaxf(fmaxf(v1.x,v1.y),fmaxf(v1.z,v1.w)));
        #pragma unroll
        for (int off = 1; off < 8; off <<= 1) mx = fmaxf(mx, __shfl_xor(mx, off, 64));
        float e[8];
        e[0]=expf(v0.x-mx); e[1]=expf(v0.y-mx); e[2]=expf(v0.z-mx); e[3]=expf(v0.w-mx);
        e[4]=expf(v1.x-mx); e[5]=expf(v1.y-mx); e[6]=expf(v1.z-mx); e[7]=expf(v1.w-mx);
        float s8 = e[0]+e[1]+e[2]+e[3]+e[4]+e[5]+e[6]+e[7];
        #pragma unroll
        for (int off = 1; off < 8; off <<= 1) s8 += __shfl_xor(s8, off, 64);
        float inv = 1.0f/s8;
        if (nb + m < N){
            float4* zp = (float4*)&z[(size_t)(nb+m)*64 + q*8];
            zp[0] = make_float4(e[0]*inv, e[1]*inv, e[2]*inv, e[3]*inv);
            zp[1] = make_float4(e[4]*inv, e[5]*inv, e[6]*inv, e[7]*inv);
        }
    }
}

// r[e] = dot64(z[src], z[dst]); 4 edges per 256-thread block
__global__ void k_dec(const int* __restrict__ eli, const float* __restrict__ z,
                      float* __restrict__ r, int EL){
    int t = threadIdx.x;
    int e = blockIdx.x*4 + (t >> 6);
    int lane = t & 63;
    if (e >= EL) return;
    int s = eli[e], d = eli[EL + e];
    float p = z[(size_t)s*64 + lane] * z[(size_t)d*64 + lane];
    #pragma unroll
    for (int off = 32; off >= 1; off >>= 1) p += __shfl_xor(p, off, 64);
    if (lane == 0) r[e] = p;
}

extern "C" void kernel_launch(void* const* d_in, const int* in_sizes, int n_in,
                              void* d_out, int out_size, void* d_ws, size_t ws_size,
                              hipStream_t stream)
{
    const float* x   = (const float*)d_in[0];
    const int*   ei  = (const int*)  d_in[1];
    const int*   eli = (const int*)  d_in[2];
    const float* h1  = (const float*)d_in[3];
    const float* h2  = (const float*)d_in[4];
    const float* Wg  = (const float*)d_in[5];
    const float* bg  = (const float*)d_in[6];
    const float* Wx  = (const float*)d_in[7];
    const float* Th  = (const float*)d_in[8];
    const float* bga = (const float*)d_in[9];
    const float* bco = (const float*)d_in[10];
    const float* wc  = (const float*)d_in[11];
    const float* Wl  = (const float*)d_in[12];
    const float* bl  = (const float*)d_in[13];

    const int N  = in_sizes[0] / FDIM;
    const int E  = in_sizes[1] / 2;
    const int EL = in_sizes[2] / 2;

    // workspace layout (4-byte units):
    float* ws   = (float*)d_ws;
    float* xw   = ws;
    float* hbuf = xw + (size_t)N*64;
    float* zbuf = hbuf + (size_t)N*64;
    float* dinv = zbuf + (size_t)N*64;
    int*   cnt  = (int*)(dinv + N);
    int*   off  = cnt + N;
    int*   cur  = off + N + 1;
    int*   csr  = cur + N;
    size_t base = (size_t)((csr + E) - (int*)ws);
    base = (base + 3) & ~(size_t)3;              // 16B align
    ushort_t* Bhi = (ushort_t*)(ws + base);      // 98304 bf16
    ushort_t* Blo = Bhi + 98304;
    ushort_t* Lhi = Blo + 98304;                 // 8192 bf16
    ushort_t* Llo = Lhi + 8192;
    float*   bsum = (float*)(Llo + 8192);        // 512 f32

    float* out = (float*)d_out;
    float* r   = out;                            // [EL]
    float* oh1 = out + EL;                       // [N*128] passthrough
    float* oC  = out + EL + (size_t)N*HDIM;      // [N*128]

    k_init  <<<(N + 255)/256, 256, 0, stream>>>(cnt, N);
    k_prep  <<<418, 256, 0, stream>>>(Wx, Th, Wl, bga, bco, Bhi, Blo, Lhi, Llo, bsum);
    k_xw    <<<(N + 3)/4, 256, 0, stream>>>(x, Wg, xw, N);
    k_deg   <<<(E + 255)/256, 256, 0, stream>>>(ei, cnt, E);
    k_scan  <<<1, 1024, 0, stream>>>(cnt, off, cur, N);
    k_dinv  <<<(N + 255)/256, 256, 0, stream>>>(cnt, dinv, N);
    k_fill  <<<(E + 255)/256, 256, 0, stream>>>(ei, cur, csr, E);
    k_gather<<<(N*16 + 255)/256, 256, 0, stream>>>(off, csr, dinv, xw, bg, hbuf, N);
    k_fused <<<(N + 31)/32, 256, 0, stream>>>(hbuf, h1, h2, Bhi, Blo, Lhi, Llo,
                                              bsum, wc, bl, oC, zbuf, N);
    hipMemcpyAsync(oh1, h1, (size_t)N*HDIM*sizeof(float), hipMemcpyDeviceToDevice, stream);
    k_dec   <<<(EL + 3)/4, 256, 0, stream>>>(eli, zbuf, r, EL);
}

// Round 4
// 269.825 us; speedup vs baseline: 4.1009x; 1.4496x over previous
//
#include <hip/hip_runtime.h>
#include <math.h>

#define FDIM 64
#define HDIM 128
#define CLSD 64

#define SCAN_ITEMS 8
#define SCAN_CHUNK 2048     // 256 threads * 8

typedef unsigned short ushort_t;
typedef short bfrag __attribute__((ext_vector_type(8)));   // 8 bf16 (4 VGPRs)
typedef float f32x4 __attribute__((ext_vector_type(4)));

__device__ __forceinline__ float sigmoidf_(float x){ return 1.0f/(1.0f+expf(-x)); }

__device__ __forceinline__ ushort_t f2bf(float f){
    unsigned int u = __float_as_uint(f);
    unsigned int r = (u + 0x7FFFu + ((u >> 16) & 1u)) >> 16;
    return (ushort_t)r;
}
__device__ __forceinline__ float bf2f(ushort_t b){
    return __uint_as_float(((unsigned int)b) << 16);
}

// ---------------- graph prep ----------------

__global__ void k_init(int* __restrict__ cnt, int N){
    int i = blockIdx.x*blockDim.x + threadIdx.x;
    if (i < N) cnt[i] = 0;
}

// xw = x @ W_gcn   ([N,64] @ [64,64]); 4 nodes per 256-thread block, W in LDS
__global__ void k_xw(const float* __restrict__ x, const float* __restrict__ W,
                     float* __restrict__ xw, int N){
    __shared__ float Wl[64*64];
    __shared__ float xs[4*64];
    int t = threadIdx.x;
    const float4* W4 = (const float4*)W;
    float4* Wl4 = (float4*)Wl;
    #pragma unroll
    for (int i = 0; i < 4; ++i) Wl4[i*256 + t] = W4[i*256 + t];
    int nb = blockIdx.x*4;
    if (nb >= N) return;
    xs[t] = x[(size_t)nb*64 + t];
    __syncthreads();
    int m = t >> 6, c = t & 63;
    const float* xr = &xs[m*64];
    float acc = 0.0f;
    #pragma unroll
    for (int k = 0; k < 64; ++k) acc += xr[k]*Wl[k*64 + c];
    xw[(size_t)(nb+m)*64 + c] = acc;
}

__global__ void k_deg(const int* __restrict__ ei, int* __restrict__ cnt, int E){
    int i = blockIdx.x*blockDim.x + threadIdx.x;
    if (i < E) atomicAdd(&cnt[ei[E + i]], 1);
}

// scan phase A: per-block local exclusive scan of cnt -> off, block totals -> bsum
__launch_bounds__(256)
__global__ void k_scanA(const int* __restrict__ cnt, int* __restrict__ off,
                        int* __restrict__ bsum, int N){
    __shared__ int s[256];
    int t = threadIdx.x;
    int base = blockIdx.x*SCAN_CHUNK + t*SCAN_ITEMS;
    int v[SCAN_ITEMS];
    int tsum = 0;
    #pragma unroll
    for (int j = 0; j < SCAN_ITEMS; ++j){
        int idx = base + j;
        v[j] = (idx < N) ? cnt[idx] : 0;
        tsum += v[j];
    }
    s[t] = tsum;
    __syncthreads();
    #pragma unroll
    for (int d = 1; d < 256; d <<= 1){
        int u = (t >= d) ? s[t-d] : 0;
        __syncthreads();
        if (t >= d) s[t] += u;
        __syncthreads();
    }
    int run = (t > 0) ? s[t-1] : 0;
    #pragma unroll
    for (int j = 0; j < SCAN_ITEMS; ++j){
        int idx = base + j;
        if (idx < N) off[idx] = run;
        run += v[j];
    }
    if (t == 255) bsum[blockIdx.x] = s[255];
}

// scan phase B: exclusive scan of block sums (nb <= 256), single block
__launch_bounds__(256)
__global__ void k_scanB(int* __restrict__ bsum, int* __restrict__ bbase, int nb){
    __shared__ int s[256];
    int t = threadIdx.x;
    s[t] = (t < nb) ? bsum[t] : 0;
    __syncthreads();
    #pragma unroll
    for (int d = 1; d < 256; d <<= 1){
        int u = (t >= d) ? s[t-d] : 0;
        __syncthreads();
        if (t >= d) s[t] += u;
        __syncthreads();
    }
    if (t < nb) bbase[t] = (t > 0) ? s[t-1] : 0;
}

// scan phase C: apply block bases; prime cur; dinv = rsqrt(deg+1); off[N] = E
__global__ void k_scanC(const int* __restrict__ cnt, int* __restrict__ off,
                        int* __restrict__ cur, float* __restrict__ dinv,
                        const int* __restrict__ bbase, int N, int E){
    int i = blockIdx.x*blockDim.x + threadIdx.x;
    if (i < N){
        int o = off[i] + bbase[i / SCAN_CHUNK];
        off[i] = o;
        cur[i] = o;
        dinv[i] = rsqrtf((float)cnt[i] + 1.0f);
    }
    if (i == 0) off[N] = E;
}

__global__ void k_fill(const int* __restrict__ ei, int* __restrict__ cur,
                       int* __restrict__ csr, int E){
    int i = blockIdx.x*blockDim.x + threadIdx.x;
    if (i < E){
        int s = ei[i], d = ei[E + i];
        int slot = atomicAdd(&cur[d], 1);
        csr[slot] = s;
    }
}

__global__ void k_gather(const int* __restrict__ off, const int* __restrict__ csr,
                         const float* __restrict__ dinv, const float* __restrict__ xw,
                         const float* __restrict__ bg, float* __restrict__ h, int N){
    int tid = blockIdx.x*256 + threadIdx.x;
    int n = tid >> 4, l = tid & 15;
    if (n >= N) return;
    int beg = off[n], end = off[n+1];
    const float4* xw4 = (const float4*)xw;
    float4 acc = make_float4(0.f,0.f,0.f,0.f);
    for (int idx = beg; idx < end; ++idx){
        int s = csr[idx];
        float w = dinv[s];
        float4 v = xw4[(size_t)s*16 + l];
        acc.x += w*v.x; acc.y += w*v.y; acc.z += w*v.z; acc.w += w*v.w;
    }
    float dn = dinv[n];
    float4 sv = xw4[(size_t)n*16 + l];
    float4 b4 = ((const float4*)bg)[l];
    acc.x = dn*(acc.x + dn*sv.x) + b4.x;
    acc.y = dn*(acc.y + dn*sv.y) + b4.y;
    acc.z = dn*(acc.z + dn*sv.z) + b4.z;
    acc.w = dn*(acc.w + dn*sv.w) + b4.w;
    ((float4*)h)[(size_t)n*16 + l] = acc;
}

// ---------------- weight prep: bf16 hi/lo splits in MFMA-fragment layout ----------------
__global__ void k_prep(const float* __restrict__ Wx, const float* __restrict__ Th,
                       const float* __restrict__ Wl,
                       const float* __restrict__ bga, const float* __restrict__ bco,
                       ushort_t* __restrict__ Bhi, ushort_t* __restrict__ Blo,
                       ushort_t* __restrict__ Lhi, ushort_t* __restrict__ Llo,
                       float* __restrict__ bsum){
    int tid = blockIdx.x*256 + threadIdx.x;
    if (tid < 98304){                       // 192 x 512 gate weights
        int k = tid >> 9, col = tid & 511;
        float v = (k < 64) ? Wx[k*512 + col] : Th[(k-64)*512 + col];
        int g = col >> 7, hc = col & 127;
        int w = hc >> 5, within = hc & 31;
        int c8 = g*2 + (within >> 4);
        int T = w*8 + c8;
        int s = k >> 5;
        int lane = ((k >> 3) & 3)*16 + (within & 15);
        int pos = ((T*6 + s)*64 + lane)*8 + (k & 7);
        ushort_t hb = f2bf(v);
        Bhi[pos] = hb;
        Blo[pos] = f2bf(v - bf2f(hb));
    } else if (tid < 106496){               // 128 x 64 Wlin
        int i = tid - 98304;
        int k = i >> 6, col = i & 63;
        float v = Wl[k*64 + col];
        int ct = col >> 4;
        int s = k >> 5;
        int lane = ((k >> 3) & 3)*16 + (col & 15);
        int pos = ((ct*4 + s)*64 + lane)*8 + (k & 7);
        ushort_t hb = f2bf(v);
        Lhi[pos] = hb;
        Llo[pos] = f2bf(v - bf2f(hb));
    } else if (tid < 107008){
        int c = tid - 106496;
        bsum[c] = bga[c] + bco[c];
    }
}

// ---------------- fused MFMA kernel ----------------
__launch_bounds__(256)
__global__ void k_fused(const float* __restrict__ h,  const float* __restrict__ h1,
                        const float* __restrict__ h2,
                        const ushort_t* __restrict__ Bhi, const ushort_t* __restrict__ Blo,
                        const ushort_t* __restrict__ Lhi, const ushort_t* __restrict__ Llo,
                        const float* __restrict__ bsum, const float* __restrict__ wc,
                        const float* __restrict__ blin,
                        float* __restrict__ outC, float* __restrict__ z, int N)
{
    __shared__ __align__(16) char smem[25088];
    ushort_t* Ahi = (ushort_t*)smem;            // [768 frags][8] bf16 = 12288 B
    ushort_t* Alo = Ahi + 6144;                 // 12288 B

    const int t    = threadIdx.x;
    const int w    = t >> 6;
    const int lane = t & 63;
    const int nb   = blockIdx.x * 32;

    #pragma unroll
    for (int ff = 0; ff < 3; ++ff){
        int f   = ff*256 + t;                   // 0..767
        int mt  = (f >= 384) ? 1 : 0;
        int rem = f - mt*384;
        int s   = rem >> 6, l = rem & 63;
        int row = mt*16 + (l & 15);
        int k0  = s*32 + ((l >> 4) & 3)*8;
        int gr  = nb + row;
        float v[8];
        if (gr < N){
            const float* src = (k0 < 64) ? (h  + (size_t)gr*64  + k0)
                                         : (h1 + (size_t)gr*128 + (k0 - 64));
            float4 p0 = ((const float4*)src)[0];
            float4 p1 = ((const float4*)src)[1];
            v[0]=p0.x; v[1]=p0.y; v[2]=p0.z; v[3]=p0.w;
            v[4]=p1.x; v[5]=p1.y; v[6]=p1.z; v[7]=p1.w;
        } else {
            #pragma unroll
            for (int j = 0; j < 8; ++j) v[j] = 0.0f;
        }
        unsigned int hp[4], lp[4];
        #pragma unroll
        for (int j = 0; j < 4; ++j){
            ushort_t h0 = f2bf(v[2*j]),  h1b = f2bf(v[2*j+1]);
            ushort_t l0 = f2bf(v[2*j]   - bf2f(h0));
            ushort_t l1 = f2bf(v[2*j+1] - bf2f(h1b));
            hp[j] = (unsigned int)h0 | ((unsigned int)h1b << 16);
            lp[j] = (unsigned int)l0 | ((unsigned int)l1  << 16);
        }
        ((int4*)Ahi)[f] = make_int4((int)hp[0],(int)hp[1],(int)hp[2],(int)hp[3]);
        ((int4*)Alo)[f] = make_int4((int)lp[0],(int)lp[1],(int)lp[2],(int)lp[3]);
    }
    __syncthreads();

    f32x4 acc[2][8];
    #pragma unroll
    for (int mt = 0; mt < 2; ++mt)
        #pragma unroll
        for (int c8 = 0; c8 < 8; ++c8)
            acc[mt][c8] = (f32x4){0.f,0.f,0.f,0.f};

    const bfrag* AhiF = (const bfrag*)Ahi;
    const bfrag* AloF = (const bfrag*)Alo;
    const bfrag* BhF  = (const bfrag*)Bhi;
    const bfrag* BlF  = (const bfrag*)Blo;

    #pragma unroll
    for (int s = 0; s < 6; ++s){
        bfrag ah0 = AhiF[(0*6 + s)*64 + lane];
        bfrag ah1 = AhiF[(1*6 + s)*64 + lane];
        bfrag al0 = AloF[(0*6 + s)*64 + lane];
        bfrag al1 = AloF[(1*6 + s)*64 + lane];
        #pragma unroll
        for (int c8 = 0; c8 < 8; ++c8){
            int T = w*8 + c8;
            bfrag bh = BhF[(T*6 + s)*64 + lane];
            bfrag bl = BlF[(T*6 + s)*64 + lane];
            acc[0][c8] = __builtin_amdgcn_mfma_f32_16x16x32_bf16(ah0, bh, acc[0][c8], 0,0,0);
            acc[0][c8] = __builtin_amdgcn_mfma_f32_16x16x32_bf16(ah0, bl, acc[0][c8], 0,0,0);
            acc[0][c8] = __builtin_amdgcn_mfma_f32_16x16x32_bf16(al0, bh, acc[0][c8], 0,0,0);
            acc[1][c8] = __builtin_amdgcn_mfma_f32_16x16x32_bf16(ah1, bh, acc[1][c8], 0,0,0);
            acc[1][c8] = __builtin_amdgcn_mfma_f32_16x16x32_bf16(ah1, bl, acc[1][c8], 0,0,0);
            acc[1][c8] = __builtin_amdgcn_mfma_f32_16x16x32_bf16(al1, bh, acc[1][c8], 0,0,0);
        }
    }
    __syncthreads();

    ushort_t* Hhi = (ushort_t*)smem;            // 8192 B (512 frags)
    ushort_t* Hlo = Hhi + 4096;                 // 8192 B
    float*    Ltile = (float*)(smem + 16384);   // [32][68] fp32 = 8704 B

    #pragma unroll
    for (int hc_t = 0; hc_t < 2; ++hc_t){
        int hc  = w*32 + hc_t*16 + (lane & 15);
        float bi = bsum[hc],       bfv = bsum[128 + hc];
        float bc = bsum[256 + hc], bo  = bsum[384 + hc];
        float wci = wc[hc], wcf = wc[128 + hc], wco = wc[256 + hc];
        #pragma unroll
        for (int mt = 0; mt < 2; ++mt){
            #pragma unroll
            for (int rr = 0; rr < 4; ++rr){
                int row = mt*16 + ((lane >> 4) & 3)*4 + rr;
                int gr  = nb + row;
                float gi = acc[mt][0 + hc_t][rr] + bi;
                float gf = acc[mt][2 + hc_t][rr] + bfv;
                float gc = acc[mt][4 + hc_t][rr] + bc;
                float go = acc[mt][6 + hc_t][rr] + bo;
                float hv = (gr < N) ? h2[(size_t)gr*128 + hc] : 0.0f;
                float I  = sigmoidf_(gi + wci*hv);
                float Fg = sigmoidf_(gf + wcf*hv);
                float C  = Fg*hv + I*tanhf(gc);
                float O  = sigmoidf_(go + wco*C);
                float hn = O*tanhf(C);
                if (gr < N) outC[(size_t)gr*128 + hc] = C;
                float hr = fmaxf(hn, 0.0f);
                int l2  = (row & 15) + (hc_t*2 + ((lane >> 3) & 1))*16;
                int pos = ((mt*4 + w)*64 + l2)*8 + (lane & 7);
                ushort_t hb = f2bf(hr);
                Hhi[pos] = hb;
                Hlo[pos] = f2bf(hr - bf2f(hb));
            }
        }
    }
    __syncthreads();

    const bfrag* HhiF = (const bfrag*)Hhi;
    const bfrag* HloF = (const bfrag*)Hlo;
    const bfrag* LhF  = (const bfrag*)Lhi;
    const bfrag* LlF  = (const bfrag*)Llo;
    f32x4 acc2[2];
    acc2[0] = (f32x4){0.f,0.f,0.f,0.f};
    acc2[1] = (f32x4){0.f,0.f,0.f,0.f};
    #pragma unroll
    for (int s = 0; s < 4; ++s){
        bfrag ah0 = HhiF[(0*4 + s)*64 + lane];
        bfrag ah1 = HhiF[(1*4 + s)*64 + lane];
        bfrag al0 = HloF[(0*4 + s)*64 + lane];
        bfrag al1 = HloF[(1*4 + s)*64 + lane];
        bfrag bh  = LhF[(w*4 + s)*64 + lane];
        bfrag bl  = LlF[(w*4 + s)*64 + lane];
        acc2[0] = __builtin_amdgcn_mfma_f32_16x16x32_bf16(ah0, bh, acc2[0], 0,0,0);
        acc2[0] = __builtin_amdgcn_mfma_f32_16x16x32_bf16(ah0, bl, acc2[0], 0,0,0);
        acc2[0] = __builtin_amdgcn_mfma_f32_16x16x32_bf16(al0, bh, acc2[0], 0,0,0);
        acc2[1] = __builtin_amdgcn_mfma_f32_16x16x32_bf16(ah1, bh, acc2[1], 0,0,0);
        acc2[1] = __builtin_amdgcn_mfma_f32_16x16x32_bf16(ah1, bl, acc2[1], 0,0,0);
        acc2[1] = __builtin_amdgcn_mfma_f32_16x16x32_bf16(al1, bh, acc2[1], 0,0,0);
    }
    {
        int cls = w*16 + (lane & 15);
        float bv = blin[cls];
        #pragma unroll
        for (int mt = 0; mt < 2; ++mt){
            #pragma unroll
            for (int rr = 0; rr < 4; ++rr){
                int row = mt*16 + ((lane >> 4) & 3)*4 + rr;
                Ltile[row*68 + cls] = acc2[mt][rr] + bv;
            }
        }
    }
    __syncthreads();

    {
        int m = t >> 3, q = t & 7;
        const float4* Lr = (const float4*)&Ltile[m*68 + q*8];
        float4 v0 = Lr[0], v1 = Lr[1];
        float mx = fmaxf(fmaxf(fmaxf(v0.x,v0.y),fmaxf(v0.z,v0.w)),
                         fmaxf(fmaxf(v1.x,v1.y),fmaxf(v1.z,v1.w)));
        #pragma unroll
        for (int off = 1; off < 8; off <<= 1) mx = fmaxf(mx, __shfl_xor(mx, off, 64));
        float e[8];
        e[0]=expf(v0.x-mx); e[1]=expf(v0.y-mx); e[2]=expf(v0.z-mx); e[3]=expf(v0.w-mx);
        e[4]=expf(v1.x-mx); e[5]=expf(v1.y-mx); e[6]=expf(v1.z-mx); e[7]=expf(v1.w-mx);
        float s8 = e[0]+e[1]+e[2]+e[3]+e[4]+e[5]+e[6]+e[7];
        #pragma unroll
        for (int off = 1; off < 8; off <<= 1) s8 += __shfl_xor(s8, off, 64);
        float inv = 1.0f/s8;
        if (nb + m < N){
            float4* zp = (float4*)&z[(size_t)(nb+m)*64 + q*8];
            zp[0] = make_float4(e[0]*inv, e[1]*inv, e[2]*inv, e[3]*inv);
            zp[1] = make_float4(e[4]*inv, e[5]*inv, e[6]*inv, e[7]*inv);
        }
    }
}

// r[e] = dot64(z[src], z[dst]); 16 lanes x float4 per edge
__global__ void k_dec(const int* __restrict__ eli, const float* __restrict__ z,
                      float* __restrict__ r, int EL){
    int tid = blockIdx.x*256 + threadIdx.x;
    int e = tid >> 4, l = tid & 15;
    if (e >= EL) return;
    int s = eli[e], d = eli[EL + e];
    float4 a = ((const float4*)z)[(size_t)s*16 + l];
    float4 b = ((const float4*)z)[(size_t)d*16 + l];
    float p = a.x*b.x + a.y*b.y + a.z*b.z + a.w*b.w;
    #pragma unroll
    for (int off = 1; off < 16; off <<= 1) p += __shfl_xor(p, off, 64);
    if (l == 0) r[e] = p;
}

extern "C" void kernel_launch(void* const* d_in, const int* in_sizes, int n_in,
                              void* d_out, int out_size, void* d_ws, size_t ws_size,
                              hipStream_t stream)
{
    const float* x   = (const float*)d_in[0];
    const int*   ei  = (const int*)  d_in[1];
    const int*   eli = (const int*)  d_in[2];
    const float* h1  = (const float*)d_in[3];
    const float* h2  = (const float*)d_in[4];
    const float* Wg  = (const float*)d_in[5];
    const float* bg  = (const float*)d_in[6];
    const float* Wx  = (const float*)d_in[7];
    const float* Th  = (const float*)d_in[8];
    const float* bga = (const float*)d_in[9];
    const float* bco = (const float*)d_in[10];
    const float* wc  = (const float*)d_in[11];
    const float* Wl  = (const float*)d_in[12];
    const float* bl  = (const float*)d_in[13];

    const int N  = in_sizes[0] / FDIM;
    const int E  = in_sizes[1] / 2;
    const int EL = in_sizes[2] / 2;
    const int NSB = (N + SCAN_CHUNK - 1) / SCAN_CHUNK;   // scan blocks (25)

    // workspace layout (4-byte units):
    float* ws   = (float*)d_ws;
    float* xw   = ws;
    float* hbuf = xw + (size_t)N*64;
    float* zbuf = hbuf + (size_t)N*64;
    float* dinv = zbuf + (size_t)N*64;
    int*   cnt  = (int*)(dinv + N);
    int*   off  = cnt + N;
    int*   cur  = off + N + 1;
    int*   csr  = cur + N;
    int*   bsc  = csr + E;          // scan block sums [<=256]
    int*   bbc  = bsc + 256;        // scan block bases [<=256]
    size_t base = (size_t)((bbc + 256) - (int*)ws);
    base = (base + 3) & ~(size_t)3;              // 16B align
    ushort_t* Bhi = (ushort_t*)(ws + base);      // 98304 bf16
    ushort_t* Blo = Bhi + 98304;
    ushort_t* Lhi = Blo + 98304;                 // 8192 bf16
    ushort_t* Llo = Lhi + 8192;
    float*   bsum = (float*)(Llo + 8192);        // 512 f32

    float* out = (float*)d_out;
    float* r   = out;                            // [EL]
    float* oh1 = out + EL;                       // [N*128] passthrough
    float* oC  = out + EL + (size_t)N*HDIM;      // [N*128]

    k_init  <<<(N + 255)/256, 256, 0, stream>>>(cnt, N);
    k_prep  <<<418, 256, 0, stream>>>(Wx, Th, Wl, bga, bco, Bhi, Blo, Lhi, Llo, bsum);
    k_xw    <<<(N + 3)/4, 256, 0, stream>>>(x, Wg, xw, N);
    k_deg   <<<(E + 255)/256, 256, 0, stream>>>(ei, cnt, E);
    k_scanA <<<NSB, 256, 0, stream>>>(cnt, off, bsc, N);
    k_scanB <<<1, 256, 0, stream>>>(bsc, bbc, NSB);
    k_scanC <<<(N + 255)/256, 256, 0, stream>>>(cnt, off, cur, dinv, bbc, N, E);
    k_fill  <<<(E + 255)/256, 256, 0, stream>>>(ei, cur, csr, E);
    k_gather<<<(N*16 + 255)/256, 256, 0, stream>>>(off, csr, dinv, xw, bg, hbuf, N);
    k_fused <<<(N + 31)/32, 256, 0, stream>>>(hbuf, h1, h2, Bhi, Blo, Lhi, Llo,
                                              bsum, wc, bl, oC, zbuf, N);
    hipMemcpyAsync(oh1, h1, (size_t)N*HDIM*sizeof(float), hipMemcpyDeviceToDevice, stream);
    k_dec   <<<(EL*16 + 255)/256, 256, 0, stream>>>(eli, zbuf, r, EL);
}